// Round 3
// baseline (661.497 us; speedup 1.0000x reference)
//
#include <hip/hip_runtime.h>

typedef unsigned long long u64;

// Pass-through that makes the value asm-defined: the compiler cannot
// rematerialize the originating load inside the loop.
__device__ __forceinline__ u64 opaque64(u64 x) { asm volatile("" : "+v"(x)); return x; }

// Workgroup barrier that orders LDS only (no vmcnt drain), so global-memory
// prefetch loads stay in flight across it.
__device__ __forceinline__ void lds_barrier() {
    asm volatile("s_waitcnt lgkmcnt(0)" ::: "memory");
    __builtin_amdgcn_s_barrier();
    asm volatile("" ::: "memory");
}

// ---------------- amax over |emb| ----------------
__global__ void amax_kernel(const float* __restrict__ emb, unsigned int* __restrict__ out) {
    const int n4 = (32000 * 256) / 4;
    float m = 0.0f;
    const float4* e4 = (const float4*)emb;
    for (int i = blockIdx.x * blockDim.x + threadIdx.x; i < n4; i += gridDim.x * blockDim.x) {
        float4 v = e4[i];
        m = fmaxf(m, fmaxf(fmaxf(fabsf(v.x), fabsf(v.y)), fmaxf(fabsf(v.z), fabsf(v.w))));
    }
#pragma unroll
    for (int off = 32; off > 0; off >>= 1) m = fmaxf(m, __shfl_down(m, off, 64));
    if ((threadIdx.x & 63) == 0) atomicMax(out, __float_as_uint(m));
}

// ---------------- bit packing, wave-cooperative ----------------
// One wave packs 16 words (1024 consecutive floats). All section boundaries
// are multiples of 16 words, so the mapping is uniform per chunk (Wfc = the
// single 8-word tail). bit = (v >= thr): thr=0 for weights; for emb,
// thr = -s/2 (== rint(v/s) >= 0 for power-of-two s, incl. the -0.0 cases).
__global__ void pack_kernel(const float* __restrict__ emb, const float* __restrict__ Wih0,
                            const float* __restrict__ Whh0, const float* __restrict__ Wih1,
                            const float* __restrict__ Whh1, const float* __restrict__ Wfc,
                            const unsigned int* __restrict__ amax_bits,
                            u64* __restrict__ embb, u64* __restrict__ w0b, u64* __restrict__ u0b,
                            u64* __restrict__ w1b, u64* __restrict__ u1b, u64* __restrict__ wfcb) {
    const int gw = (blockIdx.x * blockDim.x + threadIdx.x) >> 6;  // global wave id
    const int lane = threadIdx.x & 63;
    if (gw >= 8897) return;
    const long long wb = (long long)gw * 16;  // first packed word of this chunk

    const float* srcb; u64* dstb; int nw = 16; bool is_emb = false;
    if (wb < 128000)      { srcb = emb  + wb * 64;              dstb = embb + wb;            is_emb = true; }
    else if (wb < 130048) { srcb = Wih0 + (wb - 128000) * 64;   dstb = w0b + (wb - 128000); }
    else if (wb < 134144) { srcb = Whh0 + (wb - 130048) * 64;   dstb = u0b + (wb - 130048); }
    else if (wb < 138240) { srcb = Wih1 + (wb - 134144) * 64;   dstb = w1b + (wb - 134144); }
    else if (wb < 142336) { srcb = Whh1 + (wb - 138240) * 64;   dstb = u1b + (wb - 138240); }
    else                  { srcb = Wfc  + (wb - 142336) * 64;   dstb = wfcb + (wb - 142336); nw = 8; }

    float thr = 0.0f;
    if (is_emb) {
        float amax = __uint_as_float(*amax_bits) + 1e-12f;
        float s = exp2f(ceilf(log2f(amax / 127.0f)));   // power of two
        thr = -0.5f * s;                                 // exact
    }
    u64 mine = 0;
    for (int k0 = 0; k0 < nw; k0 += 8) {
        float v[8];
#pragma unroll
        for (int j = 0; j < 8; ++j) v[j] = srcb[(long long)(k0 + j) * 64 + lane];
#pragma unroll
        for (int j = 0; j < 8; ++j) {
            u64 bits = __ballot(v[j] >= thr);
            if (lane == k0 + j) mine = bits;
        }
    }
    if (lane < nw) dstb[lane] = mine;   // coalesced 8B stores
}

// ---------------- sequential scan, both layers pipelined ----------------
// grid = B(64) blocks (1 per CU), block = H(512) threads = 8 waves (2/SIMD).
// waves_per_eu(2,2): unlock 256-VGPR budget so the 28 u64 weight words stay
// register-resident. Double-buffered h state, 2 LDS-only barriers/step,
// embedding bits prefetched one step ahead (survive the barriers: no vmcnt
// drain). Final dense fused at the end.
__global__ __attribute__((amdgpu_flat_work_group_size(512, 512), amdgpu_waves_per_eu(2, 2)))
void scan_kernel(
    const int* __restrict__ text,
    const float* __restrict__ bih0, const float* __restrict__ bhh0,
    const float* __restrict__ bih1, const float* __restrict__ bhh1,
    const u64* __restrict__ embb, const u64* __restrict__ w0b, const u64* __restrict__ u0b,
    const u64* __restrict__ w1b, const u64* __restrict__ u1b, const u64* __restrict__ wfcb,
    float* __restrict__ out) {
    __shared__ int txt[512];
    __shared__ __align__(16) u64 h0s[2][8];   // layer-0 hidden bits, double-buffered
    __shared__ __align__(16) u64 h1s[2][8];   // layer-1 hidden bits, double-buffered

    const int tid = threadIdx.x;
    const int b = blockIdx.x;
    txt[tid] = text[b * 512 + tid];

    u64 w0[4], u0[8], w1[8], u1[8];
#pragma unroll
    for (int w = 0; w < 4; ++w) w0[w] = opaque64(w0b[tid * 4 + w]);
#pragma unroll
    for (int w = 0; w < 8; ++w) u0[w] = opaque64(u0b[tid * 8 + w]);
#pragma unroll
    for (int w = 0; w < 8; ++w) w1[w] = opaque64(w1b[tid * 8 + w]);
#pragma unroll
    for (int w = 0; w < 8; ++w) u1[w] = opaque64(u1b[tid * 8 + w]);
    const float bi0 = bih0[tid], bh0 = bhh0[tid];
    const float bi1 = bih1[tid], bh1 = bhh1[tid];

    const int lane = tid & 63;
    const int wv = tid >> 6;
    const ulonglong2* e2 = (const ulonglong2*)embb;

    lds_barrier();   // txt visible

    int tok0 = txt[0];
    ulonglong2 xa = e2[(size_t)tok0 * 2];
    ulonglong2 xc = e2[(size_t)tok0 * 2 + 1];
    int tok1 = txt[1];
    ulonglong2 na = e2[(size_t)tok1 * 2];
    ulonglong2 nc = e2[(size_t)tok1 * 2 + 1];

    // ---- t = 0 (h = 0: HU term exactly 0) ----
    {
        int mm0 = __popcll(xa.x ^ w0[0]) + __popcll(xa.y ^ w0[1])
                + __popcll(xc.x ^ w0[2]) + __popcll(xc.y ^ w0[3]);
        float c0 = ((float)(256 - 2 * mm0) + bi0) + bh0;
        u64 b0 = __ballot(c0 >= 0.0f);
        if (lane == 0) h0s[1][wv] = b0;
        lds_barrier();
        const ulonglong2* h0n = (const ulonglong2*)h0s[1];
        int mx1 = 0;
#pragma unroll
        for (int w = 0; w < 4; ++w) {
            ulonglong2 hv = h0n[w];
            mx1 += __popcll(hv.x ^ w1[2 * w]) + __popcll(hv.y ^ w1[2 * w + 1]);
        }
        float c1 = ((float)(512 - 2 * mx1) + bi1) + bh1;
        u64 b1 = __ballot(c1 >= 0.0f);
        if (lane == 0) h1s[1][wv] = b1;
        lds_barrier();
        xa = na; xc = nc;
    }

#pragma unroll 2
    for (int t = 1; t < 512; ++t) {
        const int r = t & 1;
        // prefetch next step's embedding bits (survives both barriers)
        const int tokn = txt[(t + 1) & 511];
        ulonglong2 pa = e2[(size_t)tokn * 2];
        ulonglong2 pc = e2[(size_t)tokn * 2 + 1];

        // recurrent popcounts for BOTH layers read old state (buffer r)
        const ulonglong2* h0p = (const ulonglong2*)h0s[r];
        const ulonglong2* h1p = (const ulonglong2*)h1s[r];
        int mh0 = 0, mh1 = 0;
#pragma unroll
        for (int w = 0; w < 4; ++w) {
            ulonglong2 hv = h0p[w];
            mh0 += __popcll(hv.x ^ u0[2 * w]) + __popcll(hv.y ^ u0[2 * w + 1]);
        }
#pragma unroll
        for (int w = 0; w < 4; ++w) {
            ulonglong2 hv = h1p[w];
            mh1 += __popcll(hv.x ^ u1[2 * w]) + __popcll(hv.y ^ u1[2 * w + 1]);
        }
        int mm0 = __popcll(xa.x ^ w0[0]) + __popcll(xa.y ^ w0[1])
                + __popcll(xc.x ^ w0[2]) + __popcll(xc.y ^ w0[3]);

        // acc0 = fl(fl(fl(M0+bih0)+bhh0)+HU0), exact JAX association
        float c0 = ((float)(256 - 2 * mm0) + bi0) + bh0;
        float acc0 = c0 + (float)(512 - 2 * mh0);
        u64 b0 = __ballot(acc0 >= 0.0f);
        if (lane == 0) h0s[r ^ 1][wv] = b0;
        lds_barrier();   // A: old-state reads done + new h0 visible

        const ulonglong2* h0n = (const ulonglong2*)h0s[r ^ 1];
        int mx1 = 0;
#pragma unroll
        for (int w = 0; w < 4; ++w) {
            ulonglong2 hv = h0n[w];
            mx1 += __popcll(hv.x ^ w1[2 * w]) + __popcll(hv.y ^ w1[2 * w + 1]);
        }
        float c1 = ((float)(512 - 2 * mx1) + bi1) + bh1;
        float acc1 = c1 + (float)(512 - 2 * mh1);
        u64 b1 = __ballot(acc1 >= 0.0f);
        if (lane == 0) h1s[r ^ 1][wv] = b1;
        lds_barrier();   // B: new h1 visible for next step's top reads

        xa = pa; xc = pc;
    }

    // t=511 (r=1) wrote buffers [0]; last barrier ordered them.
    // Fused final dense: out[layer*64 + b] = hT . sign(Wfc)
    if (tid < 2) {
        const u64* h = (tid == 0) ? h0s[0] : h1s[0];
        int mm = 0;
#pragma unroll
        for (int w = 0; w < 8; ++w) mm += __popcll(h[w] ^ wfcb[w]);
        out[tid * 64 + b] = (float)(512 - 2 * mm);
    }
}

extern "C" void kernel_launch(void* const* d_in, const int* in_sizes, int n_in,
                              void* d_out, int out_size, void* d_ws, size_t ws_size,
                              hipStream_t stream) {
    const int* text = (const int*)d_in[0];
    // d_in[1] = text_lengths : unused by the reference computation
    const float* emb = (const float*)d_in[2];
    const float* Wih0 = (const float*)d_in[3];
    const float* Whh0 = (const float*)d_in[4];
    const float* bih0 = (const float*)d_in[5];
    const float* bhh0 = (const float*)d_in[6];
    const float* Wih1 = (const float*)d_in[7];
    const float* Whh1 = (const float*)d_in[8];
    const float* bih1 = (const float*)d_in[9];
    const float* bhh1 = (const float*)d_in[10];
    const float* Wfc = (const float*)d_in[11];
    float* out = (float*)d_out;

    // workspace layout (u64 units): [0..7]=amax scalar (+pad), then bit arrays
    u64* ws = (u64*)d_ws;
    u64* embb = ws + 8;            // 32000*4 = 128000 words
    u64* w0b = embb + 128000;      // 512*4   = 2048
    u64* u0b = w0b + 2048;         // 512*8   = 4096
    u64* w1b = u0b + 4096;         // 4096
    u64* u1b = w1b + 4096;         // 4096
    u64* wfcb = u1b + 4096;        // 8
    unsigned int* amax = (unsigned int*)d_ws;

    hipMemsetAsync(d_ws, 0, 64, stream);  // amax := 0 (ws is poisoned 0xAA)
    amax_kernel<<<2048, 256, 0, stream>>>(emb, amax);
    pack_kernel<<<(8897 * 64 + 255) / 256, 256, 0, stream>>>(emb, Wih0, Whh0, Wih1, Whh1, Wfc,
                                                             amax, embb, w0b, u0b, w1b, u1b, wfcb);
    scan_kernel<<<64, 512, 0, stream>>>(text, bih0, bhh0, bih1, bhh1,
                                        embb, w0b, u0b, w1b, u1b, wfcb, out);
}

// Round 5
// 503.721 us; speedup vs baseline: 1.3132x; 1.3132x over previous
//
#include <hip/hip_runtime.h>

typedef unsigned long long u64;

// Pass-through that makes the value asm-defined: the compiler cannot
// rematerialize the originating load inside the loop.
__device__ __forceinline__ u64 opaque64(u64 x) { asm volatile("" : "+v"(x)); return x; }

// Workgroup barrier that orders LDS only (no vmcnt drain), so global-memory
// prefetch loads stay in flight across it.
__device__ __forceinline__ void lds_barrier() {
    asm volatile("s_waitcnt lgkmcnt(0)" ::: "memory");
    __builtin_amdgcn_s_barrier();
    asm volatile("" ::: "memory");
}

// ---------------- amax over |emb| ----------------
__global__ void amax_kernel(const float* __restrict__ emb, unsigned int* __restrict__ out) {
    const int n4 = (32000 * 256) / 4;
    float m = 0.0f;
    const float4* e4 = (const float4*)emb;
    for (int i = blockIdx.x * blockDim.x + threadIdx.x; i < n4; i += gridDim.x * blockDim.x) {
        float4 v = e4[i];
        m = fmaxf(m, fmaxf(fmaxf(fabsf(v.x), fabsf(v.y)), fmaxf(fabsf(v.z), fabsf(v.w))));
    }
#pragma unroll
    for (int off = 32; off > 0; off >>= 1) m = fmaxf(m, __shfl_down(m, off, 64));
    if ((threadIdx.x & 63) == 0) atomicMax(out, __float_as_uint(m));
}

// ---------------- bit packing, wave-cooperative ----------------
__global__ void pack_kernel(const float* __restrict__ emb, const float* __restrict__ Wih0,
                            const float* __restrict__ Whh0, const float* __restrict__ Wih1,
                            const float* __restrict__ Whh1, const float* __restrict__ Wfc,
                            const unsigned int* __restrict__ amax_bits,
                            u64* __restrict__ embb, u64* __restrict__ w0b, u64* __restrict__ u0b,
                            u64* __restrict__ w1b, u64* __restrict__ u1b, u64* __restrict__ wfcb) {
    const int gw = (blockIdx.x * blockDim.x + threadIdx.x) >> 6;  // global wave id
    const int lane = threadIdx.x & 63;
    if (gw >= 8897) return;
    const long long wb = (long long)gw * 16;  // first packed word of this chunk

    const float* srcb; u64* dstb; int nw = 16; bool is_emb = false;
    if (wb < 128000)      { srcb = emb  + wb * 64;              dstb = embb + wb;            is_emb = true; }
    else if (wb < 130048) { srcb = Wih0 + (wb - 128000) * 64;   dstb = w0b + (wb - 128000); }
    else if (wb < 134144) { srcb = Whh0 + (wb - 130048) * 64;   dstb = u0b + (wb - 130048); }
    else if (wb < 138240) { srcb = Wih1 + (wb - 134144) * 64;   dstb = w1b + (wb - 134144); }
    else if (wb < 142336) { srcb = Whh1 + (wb - 138240) * 64;   dstb = u1b + (wb - 138240); }
    else                  { srcb = Wfc  + (wb - 142336) * 64;   dstb = wfcb + (wb - 142336); nw = 8; }

    float thr = 0.0f;
    if (is_emb) {
        float amax = __uint_as_float(*amax_bits) + 1e-12f;
        float s = exp2f(ceilf(log2f(amax / 127.0f)));   // power of two
        thr = -0.5f * s;                                 // == rint(v/s) >= 0
    }
    u64 mine = 0;
    for (int k0 = 0; k0 < nw; k0 += 8) {
        float v[8];
#pragma unroll
        for (int j = 0; j < 8; ++j) v[j] = srcb[(long long)(k0 + j) * 64 + lane];
#pragma unroll
        for (int j = 0; j < 8; ++j) {
            u64 bits = __ballot(v[j] >= thr);
            if (lane == k0 + j) mine = bits;
        }
    }
    if (lane < nw) dstb[lane] = mine;   // coalesced 8B stores
}

// ---------------- layer-0 input-threshold precompute ----------------
// T0[b][t][h] = floor((512 + xw)/2), xw = fl(fl((256-2*mm0)+bih0)+bhh0).
// Exact: sign(fl(xw + (512-2*mh0))) >= 0  <=>  mh0 <= T0   (h=0 case: mh0:=256).
// Stored as i16 pairs: dword index (b*256 + t/2)*512 + h holds {t even, t odd}.
__global__ void xw_kernel(const int* __restrict__ text,
                          const float* __restrict__ bih0, const float* __restrict__ bhh0,
                          const u64* __restrict__ embb, const u64* __restrict__ w0b,
                          int* __restrict__ T0p) {
    const int tid = threadIdx.x;
    const int b = blockIdx.x >> 6;
    const int tg = blockIdx.x & 63;   // covers t = tg*8 .. tg*8+7
    __shared__ int toks[8];
    if (tid < 8) toks[tid] = text[b * 512 + tg * 8 + tid];
    u64 w0[4];
#pragma unroll
    for (int w = 0; w < 4; ++w) w0[w] = w0b[tid * 4 + w];
    const float bi = bih0[tid], bh = bhh0[tid];
    __syncthreads();
    int lo = 0;
#pragma unroll
    for (int t8 = 0; t8 < 8; ++t8) {
        const u64* xb = embb + (size_t)toks[t8] * 4;
        int mm = 0;
#pragma unroll
        for (int w = 0; w < 4; ++w) mm += __popcll(xb[w] ^ w0[w]);
        float xw = ((float)(256 - 2 * mm) + bi) + bh;
        int T0 = (int)floor((512.0 + (double)xw) * 0.5);   // exact (<= 41 mantissa bits)
        if ((t8 & 1) == 0) lo = T0;
        else {
            int t = tg * 8 + t8;
            T0p[((size_t)b * 256 + (t >> 1)) * 512 + tid] = (lo & 0xffff) | (T0 << 16);
        }
    }
}

// ---------------- sequential scan: layer-1 lagged one step ----------------
// Phase p computes h0[p] (from h0[p-1]) and h1[p-1] (from h0[p-1], h1[p-2]) --
// both inputs were published at the previous barrier => ONE barrier per phase.
// State LDS: st[par][0..7]=h0, st[par][8..15]=h1; read st[(p-1)&1], write st[p&1].
__global__ __attribute__((amdgpu_flat_work_group_size(512, 512), amdgpu_waves_per_eu(2, 2)))
void scan_kernel(const float* __restrict__ bih1, const float* __restrict__ bhh1,
                 const u64* __restrict__ u0b, const u64* __restrict__ w1b,
                 const u64* __restrict__ u1b, const u64* __restrict__ wfcb,
                 const int* __restrict__ T0d, float* __restrict__ out) {
    __shared__ __align__(16) u64 st[2][16];

    const int tid = threadIdx.x;
    const int b = blockIdx.x;
    u64 u0[8], w1[8], u1[8];
#pragma unroll
    for (int w = 0; w < 8; ++w) u0[w] = opaque64(u0b[tid * 8 + w]);
#pragma unroll
    for (int w = 0; w < 8; ++w) w1[w] = opaque64(w1b[tid * 8 + w]);
#pragma unroll
    for (int w = 0; w < 8; ++w) u1[w] = opaque64(u1b[tid * 8 + w]);
    const float bi1 = bih1[tid], bh1 = bhh1[tid];
    const int lane = tid & 63;
    const int wv = tid >> 6;

    const int* T0row = T0d + (size_t)b * (256 * 512) + tid;  // +512 per t-pair
    const int* Tlast = T0row + 255 * 512;   // last valid pair {t510,t511}
    int pc = T0row[0];          // pair {t0,t1}   (consumed in phases 0,1)
    int pn = T0row[512];        // pair {t2,t3}
    int p2 = T0row[1024];       // pair {t4,t5}
    const int* Tptr = T0row + 1536;

    // ---- phase 0: h0[0] (h0[-1]=0 -> condition 256 <= T0(t0)) ----
    {
        u64 b0 = __ballot(256 <= (int)(short)(pc & 0xffff));
        if (lane == 0) st[0][wv] = b0;
        lds_barrier();
    }
    // ---- phase 1: h0[1] (T0(t1)); h1[0] with forced HU=0 (cmp c1 >= 0) ----
    {
        const ulonglong2* h0p = (const ulonglong2*)&st[0][0];
        int mh0 = 0, mx1 = 0;
#pragma unroll
        for (int w = 0; w < 4; ++w) {
            ulonglong2 hv = h0p[w];
            mh0 += __popcll(hv.x ^ u0[2 * w]) + __popcll(hv.y ^ u0[2 * w + 1]);
            mx1 += __popcll(hv.x ^ w1[2 * w]) + __popcll(hv.y ^ w1[2 * w + 1]);
        }
        u64 b0 = __ballot(mh0 <= (int)(short)(pc >> 16));
        float c1 = ((float)(512 - 2 * mx1) + bi1) + bh1;
        u64 b1 = __ballot(c1 >= 0.0f);
        if (lane == 0) { st[1][wv] = b0; st[1][8 + wv] = b1; }
        lds_barrier();
    }

#define QRNN_PHASE(RD, WR, T0IMM)                                                   \
    {                                                                               \
        const ulonglong2* h0p = (const ulonglong2*)&st[RD][0];                      \
        const ulonglong2* h1p = (const ulonglong2*)&st[RD][8];                      \
        int mh0 = 0, mx1 = 0, mh1 = 0;                                              \
        _Pragma("unroll")                                                           \
        for (int w = 0; w < 4; ++w) {                                               \
            ulonglong2 hv = h0p[w];                                                 \
            mh0 += __popcll(hv.x ^ u0[2 * w]) + __popcll(hv.y ^ u0[2 * w + 1]);     \
            mx1 += __popcll(hv.x ^ w1[2 * w]) + __popcll(hv.y ^ w1[2 * w + 1]);     \
        }                                                                           \
        _Pragma("unroll")                                                           \
        for (int w = 0; w < 4; ++w) {                                               \
            ulonglong2 hv = h1p[w];                                                 \
            mh1 += __popcll(hv.x ^ u1[2 * w]) + __popcll(hv.y ^ u1[2 * w + 1]);     \
        }                                                                           \
        u64 b0 = __ballot(mh0 <= (int)(T0IMM));                                     \
        float c1 = ((float)(512 - 2 * mx1) + bi1) + bh1;                            \
        u64 b1 = __ballot(c1 >= (float)(2 * mh1 - 512));                            \
        if (lane == 0) { st[WR][wv] = b0; st[WR][8 + wv] = b1; }                    \
        lds_barrier();                                                              \
    }

    // ---- main loop: phases p (even, rd=1,wr=0) and p+1 (odd, rd=0,wr=1).
    // Iteration p consumes pn = pair {t_p, t_{p+1}} (pc was used by phases 0/1).
    for (int p = 2; p < 512; p += 2) {
        const int* tp = (Tptr > Tlast) ? Tlast : Tptr;   // clamp tail prefetch
        int pf = *tp; Tptr += 512;   // pair {t_{p+4}, t_{p+5}}
        QRNN_PHASE(1, 0, (short)(pn & 0xffff));
        QRNN_PHASE(0, 1, (short)(pn >> 16));
        pn = p2; p2 = pf;
    }
#undef QRNN_PHASE

    // ---- phase 512: h1[511] only (inputs h0[511], h1[510] in st[1]) ----
    {
        const ulonglong2* h0p = (const ulonglong2*)&st[1][0];
        const ulonglong2* h1p = (const ulonglong2*)&st[1][8];
        int mx1 = 0, mh1 = 0;
#pragma unroll
        for (int w = 0; w < 4; ++w) {
            ulonglong2 hv = h0p[w];
            mx1 += __popcll(hv.x ^ w1[2 * w]) + __popcll(hv.y ^ w1[2 * w + 1]);
        }
#pragma unroll
        for (int w = 0; w < 4; ++w) {
            ulonglong2 hv = h1p[w];
            mh1 += __popcll(hv.x ^ u1[2 * w]) + __popcll(hv.y ^ u1[2 * w + 1]);
        }
        float c1 = ((float)(512 - 2 * mx1) + bi1) + bh1;
        u64 b1 = __ballot(c1 >= (float)(2 * mh1 - 512));
        if (lane == 0) st[0][8 + wv] = b1;
        lds_barrier();
    }
    // ---- fused final dense: out[layer*64 + b] = hT . sign(Wfc) ----
    if (tid < 2) {
        const u64* h = (tid == 0) ? &st[1][0] : &st[0][8];  // h0[511] / h1[511]
        int mm = 0;
#pragma unroll
        for (int w = 0; w < 8; ++w) mm += __popcll(h[w] ^ wfcb[w]);
        out[tid * 64 + b] = (float)(512 - 2 * mm);
    }
}

extern "C" void kernel_launch(void* const* d_in, const int* in_sizes, int n_in,
                              void* d_out, int out_size, void* d_ws, size_t ws_size,
                              hipStream_t stream) {
    const int* text = (const int*)d_in[0];
    // d_in[1] = text_lengths : unused by the reference computation
    const float* emb = (const float*)d_in[2];
    const float* Wih0 = (const float*)d_in[3];
    const float* Whh0 = (const float*)d_in[4];
    const float* bih0 = (const float*)d_in[5];
    const float* bhh0 = (const float*)d_in[6];
    const float* Wih1 = (const float*)d_in[7];
    const float* Whh1 = (const float*)d_in[8];
    const float* bih1 = (const float*)d_in[9];
    const float* bhh1 = (const float*)d_in[10];
    const float* Wfc = (const float*)d_in[11];
    float* out = (float*)d_out;

    // workspace layout (u64 units)
    u64* ws = (u64*)d_ws;
    u64* embb = ws + 8;            // 32000*4 = 128000 words
    u64* w0b = embb + 128000;      // 2048
    u64* u0b = w0b + 2048;         // 4096
    u64* w1b = u0b + 4096;         // 4096
    u64* u1b = w1b + 4096;         // 4096
    u64* wfcb = u1b + 4096;        // 8
    int* T0p = (int*)(wfcb + 8);   // 64*256*512 dwords = 32 MB
    unsigned int* amax = (unsigned int*)d_ws;

    hipMemsetAsync(d_ws, 0, 64, stream);  // amax := 0 (ws is poisoned 0xAA)
    amax_kernel<<<2048, 256, 0, stream>>>(emb, amax);
    pack_kernel<<<(8897 * 64 + 255) / 256, 256, 0, stream>>>(emb, Wih0, Whh0, Wih1, Whh1, Wfc,
                                                             amax, embb, w0b, u0b, w1b, u1b, wfcb);
    xw_kernel<<<64 * 64, 512, 0, stream>>>(text, bih0, bhh0, embb, w0b, T0p);
    scan_kernel<<<64, 512, 0, stream>>>(bih1, bhh1, u0b, w1b, u1b, wfcb, T0p, out);
}